// Round 4
// baseline (31083.759 us; speedup 1.0000x reference)
//
#include <hip/hip_runtime.h>
#include <hip/hip_bf16.h>

// Problem constants
#define NHEAD 8
#define SLEN 64
#define TLEN 32
#define NNODE 512
#define NEDGE 16384
#define NLAYER 4

// ---------------------------------------------------------------------------
// GEMM: C[M,N] = A[M,K] @ B[K,N] + bias[N], optional relu.
// BM=BN=64, BK=16, 256 threads, 4x4 microtile. M,N mult of 64; K mult of 16.
// ---------------------------------------------------------------------------
__global__ __launch_bounds__(256) void gemm_bias(
    const float* __restrict__ A, int lda,
    const float* __restrict__ B, int ldb,
    const float* __restrict__ bias,
    float* __restrict__ C, int ldc,
    int M, int N, int K, int relu)
{
    __shared__ float As[16][68];
    __shared__ float Bs[16][68];
    const int tid = threadIdx.x;
    const int tx = tid & 15, ty = tid >> 4;
    const int m0 = blockIdx.y * 64, n0 = blockIdx.x * 64;
    const int liA_m = tid >> 2;
    const int liA_k = (tid & 3) * 4;
    const int liB_n = (tid & 15) * 4;
    const int liB_k = tid >> 4;
    float acc[4][4] = {};
    for (int k0 = 0; k0 < K; k0 += 16) {
        float4 av = *reinterpret_cast<const float4*>(&A[(size_t)(m0 + liA_m) * lda + k0 + liA_k]);
        float4 bv = *reinterpret_cast<const float4*>(&B[(size_t)(k0 + liB_k) * ldb + n0 + liB_n]);
        As[liA_k + 0][liA_m] = av.x;
        As[liA_k + 1][liA_m] = av.y;
        As[liA_k + 2][liA_m] = av.z;
        As[liA_k + 3][liA_m] = av.w;
        *reinterpret_cast<float4*>(&Bs[liB_k][liB_n]) = bv;
        __syncthreads();
        #pragma unroll
        for (int kk = 0; kk < 16; ++kk) {
            float4 a4 = *reinterpret_cast<const float4*>(&As[kk][ty * 4]);
            float4 b4 = *reinterpret_cast<const float4*>(&Bs[kk][tx * 4]);
            float a[4] = {a4.x, a4.y, a4.z, a4.w};
            float b[4] = {b4.x, b4.y, b4.z, b4.w};
            #pragma unroll
            for (int i = 0; i < 4; ++i)
                #pragma unroll
                for (int j = 0; j < 4; ++j)
                    acc[i][j] += a[i] * b[j];
        }
        __syncthreads();
    }
    #pragma unroll
    for (int i = 0; i < 4; ++i) {
        const int m = m0 + ty * 4 + i;
        #pragma unroll
        for (int j = 0; j < 4; ++j) {
            const int n = n0 + tx * 4 + j;
            float v = acc[i][j] + bias[n];
            if (relu) v = fmaxf(v, 0.0f);
            C[(size_t)m * ldc + n] = v;
        }
    }
}

// ---------------------------------------------------------------------------
// Permute seq-first (L,512,CH) -> node-major (512,L,CH). Elementwise gather.
// ---------------------------------------------------------------------------
__global__ __launch_bounds__(256) void permute_in(
    const float* __restrict__ in, float* __restrict__ out, int L, int CH, int total)
{
    const int idx = blockIdx.x * 256 + threadIdx.x;
    if (idx >= total) return;
    const int c = idx % CH;
    const int r = idx / CH;       // r = l*512 + n
    const int n = r & 511;
    const int l = r >> 9;
    out[((size_t)n * L + l) * CH + c] = in[idx];
}

// ---------------------------------------------------------------------------
// Fused MHA, node-major: block = (n_local, h). Q rows n*LQ+r, K/V rows n*LK+r.
// One wave. Online softmax. In-place safe: block (n,h) reads and writes only
// its own (node n, head-h columns) region.
// ---------------------------------------------------------------------------
template<int LQ, int LK, bool CAUSAL>
__global__ __launch_bounds__(64) void attn_kernel(
    const float* __restrict__ Q, int ldq,
    const float* __restrict__ Kp, int ldk,
    const float* __restrict__ Vp, int ldv,
    float* __restrict__ O, int ldo)
{
    __shared__ float qs[LQ][68];
    __shared__ float ks[LK][68];
    __shared__ float vs[LK][68];
    const int n = blockIdx.x >> 3;
    const int h = blockIdx.x & 7;
    const int lane = threadIdx.x;
    const int col = h * 64 + lane;
    for (int r = 0; r < LQ; ++r) qs[r][lane] = Q[(size_t)(n * LQ + r) * ldq + col];
    for (int r = 0; r < LK; ++r) ks[r][lane] = Kp[(size_t)(n * LK + r) * ldk + col];
    for (int r = 0; r < LK; ++r) vs[r][lane] = Vp[(size_t)(n * LK + r) * ldv + col];
    __syncthreads();
    float o[64];
    if (lane < LQ) {
        float qr[64];
        #pragma unroll
        for (int j = 0; j < 64; ++j) { qr[j] = qs[lane][j]; o[j] = 0.0f; }
        float m = -1e30f, l = 0.0f;
        const int kend = CAUSAL ? (lane + 1) : LK;
        for (int kk = 0; kk < kend; ++kk) {
            float s = 0.0f;
            #pragma unroll
            for (int j = 0; j < 16; ++j) {
                float4 kv = *reinterpret_cast<const float4*>(&ks[kk][j * 4]);
                s += qr[4*j+0]*kv.x + qr[4*j+1]*kv.y + qr[4*j+2]*kv.z + qr[4*j+3]*kv.w;
            }
            s *= 0.125f;  // 1/sqrt(64)
            const float mn = fmaxf(m, s);
            const float sc = expf(m - mn);   // 0 on first iter
            const float p  = expf(s - mn);
            l = l * sc + p;
            #pragma unroll
            for (int j = 0; j < 16; ++j) {
                float4 vv = *reinterpret_cast<const float4*>(&vs[kk][j * 4]);
                o[4*j+0] = o[4*j+0] * sc + p * vv.x;
                o[4*j+1] = o[4*j+1] * sc + p * vv.y;
                o[4*j+2] = o[4*j+2] * sc + p * vv.z;
                o[4*j+3] = o[4*j+3] * sc + p * vv.w;
            }
            m = mn;
        }
        const float inv = 1.0f / l;
        #pragma unroll
        for (int j = 0; j < 64; ++j) o[j] *= inv;
    }
    __syncthreads();
    if (lane < LQ) {
        #pragma unroll
        for (int j = 0; j < 64; ++j) qs[lane][j] = o[j];
    }
    __syncthreads();
    for (int r = 0; r < LQ; ++r) O[(size_t)(n * LQ + r) * ldo + col] = qs[r][lane];
}

// ---------------------------------------------------------------------------
// LayerNorm over last dim (512): out = LN(x [+ res]) * g + b. Wave per row.
// ---------------------------------------------------------------------------
__global__ __launch_bounds__(256) void ln_kernel(
    const float* __restrict__ X, const float* __restrict__ R,
    const float* __restrict__ g, const float* __restrict__ b,
    float* __restrict__ out, int ntok)
{
    const int wid = threadIdx.x >> 6, lane = threadIdx.x & 63;
    const int row = blockIdx.x * 4 + wid;
    if (row >= ntok) return;
    const size_t base = (size_t)row * 512;
    float v[8];
    float s = 0.0f;
    const bool hasR = (R != nullptr);
    #pragma unroll
    for (int j = 0; j < 8; ++j) {
        float t = X[base + j * 64 + lane];
        if (hasR) t += R[base + j * 64 + lane];
        v[j] = t; s += t;
    }
    #pragma unroll
    for (int d = 32; d >= 1; d >>= 1) s += __shfl_xor(s, d, 64);
    const float mean = s * (1.0f / 512.0f);
    float vs = 0.0f;
    #pragma unroll
    for (int j = 0; j < 8; ++j) { const float d = v[j] - mean; vs += d * d; }
    #pragma unroll
    for (int d = 32; d >= 1; d >>= 1) vs += __shfl_xor(vs, d, 64);
    const float rstd = rsqrtf(vs * (1.0f / 512.0f) + 1e-5f);
    #pragma unroll
    for (int j = 0; j < 8; ++j) {
        const int c = j * 64 + lane;
        out[base + c] = (v[j] - mean) * rstd * g[c] + b[c];
    }
}

// ---------------------------------------------------------------------------
// Sinusoidal positional encoding add, node-major (row = n*L + l)
// ---------------------------------------------------------------------------
__global__ __launch_bounds__(256) void add_posenc(float* __restrict__ x, int L, int total)
{
    const int idx = blockIdx.x * 256 + threadIdx.x;
    if (idx >= total) return;
    const int d = idx & 511;
    const int row = idx >> 9;
    const int l = row % L;
    const int i2 = d & ~1;
    const float freq = expf(-9.210340371976184f * (float)i2 / 512.0f); // ln(10000)
    const float a = (float)l * freq;
    x[idx] += (d & 1) ? cosf(a) : sinf(a);
}

// ---------------------------------------------------------------------------
// CSR build for GATv2 (incoming edges per dst node)
// ---------------------------------------------------------------------------
__global__ void zero_ints(int* __restrict__ p, int n)
{
    const int i = blockIdx.x * 256 + threadIdx.x;
    if (i < n) p[i] = 0;
}

__global__ void count_deg(const int* __restrict__ edst, int* __restrict__ deg)
{
    const int e = blockIdx.x * 256 + threadIdx.x;
    if (e < NEDGE) atomicAdd(&deg[edst[e]], 1);
}

__global__ void scan512(const int* __restrict__ deg, int* __restrict__ off)
{
    __shared__ int s[512];
    const int tid = threadIdx.x;
    s[tid] = deg[tid];
    __syncthreads();
    for (int d = 1; d < 512; d <<= 1) {
        const int t = (tid >= d) ? s[tid - d] : 0;
        __syncthreads();
        s[tid] += t;
        __syncthreads();
    }
    off[tid + 1] = s[tid];
    if (tid == 0) off[0] = 0;
}

__global__ void fill_eid(const int* __restrict__ edst, const int* __restrict__ off,
                         int* __restrict__ cur, int* __restrict__ eid)
{
    const int e = blockIdx.x * 256 + threadIdx.x;
    if (e < NEDGE) {
        const int d = edst[e];
        const int pos = off[d] + atomicAdd(&cur[d], 1);
        eid[pos] = e;
    }
}

// ---------------------------------------------------------------------------
// GATv2 layer: block per (t, dst). 256 threads = 8 heads x 32 ch.
// xl/xr node-major (row = n*TLEN + t). Non-final out node-major (float);
// final out t-major FLOAT32 (reference output dtype) with +bias, relu.
// ---------------------------------------------------------------------------
template<bool FINAL>
__global__ __launch_bounds__(256) void gatv2_kernel(
    const float* __restrict__ xl, const float* __restrict__ xr,
    const float* __restrict__ att, const float* __restrict__ bias,
    const int* __restrict__ off, const int* __restrict__ eid,
    const int* __restrict__ esrc,
    float* __restrict__ outf, float* __restrict__ outd)
{
    const int blk = blockIdx.x;       // t*NNODE + i
    const int i = blk & (NNODE - 1);
    const int t = blk >> 9;
    const int tid = threadIdx.x;
    const float xrv = xr[((size_t)i * TLEN + t) * 256 + tid];
    const float av = att[tid];
    const int e0 = off[i], e1 = off[i + 1];
    float m = -1e30f, den = 0.0f, acc = 0.0f;
    for (int idx = e0; idx < e1; ++idx) {
        const int e = eid[idx];
        const int s = esrc[e];
        const float xlv = xl[((size_t)s * TLEN + t) * 256 + tid];
        float z = xlv + xrv;
        z = (z > 0.0f) ? z : 0.2f * z;  // leaky_relu(0.2)
        float w = z * av;
        #pragma unroll
        for (int d = 16; d >= 1; d >>= 1) w += __shfl_xor(w, d, 32);
        const float mn = fmaxf(m, w);
        const float sc = expf(m - mn);
        const float p  = expf(w - mn);
        den = den * sc + p;
        acc = acc * sc + p * xlv;
        m = mn;
    }
    float o = (den > 0.0f) ? acc / den : 0.0f;
    o += bias[tid];
    if (FINAL) {
        o = fmaxf(o, 0.0f);
        outd[(size_t)blk * 256 + tid] = o;       // fp32 output, t-major
    } else {
        outf[((size_t)i * TLEN + t) * 256 + tid] = o;
    }
}

// ---------------------------------------------------------------------------
// Canary: fill fp32 output with 336. If the final writer silently fails,
// absmax ~ 335 tells us.
// ---------------------------------------------------------------------------
__global__ __launch_bounds__(256) void canary_fill(float* __restrict__ out, int total)
{
    const int idx = blockIdx.x * 256 + threadIdx.x;
    if (idx < total) out[idx] = 336.0f;
}

// ---------------------------------------------------------------------------
// Diagnostics: runs LAST. Samples each stage's output; writes a code to
// out[0] ONLY if an anomaly is found (earliest failing stage wins).
// codes: MEM 1024/1536/2048 (nan/zero/big), Y 4096/6144/8192,
//        F 16384/24576/32768, Ib 65536/98304/131072, G2 262144/393216/524288
// ---------------------------------------------------------------------------
__device__ int diag_check(const float* p, size_t n)
{
    bool nan = false, nz = false; float mx = 0.0f;
    const size_t stride = n / 256;
    for (int i = 0; i < 256; ++i) {
        const float v = p[(size_t)i * stride];
        if (v != v || fabsf(v) > 1e30f) nan = true;
        if (v != 0.0f) nz = true;
        const float a = fabsf(v);
        if (a > mx) mx = a;
    }
    if (nan) return 1;
    if (!nz) return 2;
    if (mx > 1e4f) return 3;
    return 0;
}

__global__ void diag_kernel(const float* __restrict__ MEM, const float* __restrict__ Y,
                            const float* __restrict__ F, const float* __restrict__ Ib,
                            const float* __restrict__ G2, float* __restrict__ out0)
{
    if (threadIdx.x != 0 || blockIdx.x != 0) return;
    float code = 0.0f;
    int r;
    if ((r = diag_check(MEM, 16777216)) != 0)      code = 1024.0f * (r == 1 ? 1.0f : (r == 2 ? 1.5f : 2.0f));
    else if ((r = diag_check(Y, 8388608)) != 0)    code = 4096.0f * (r == 1 ? 1.0f : (r == 2 ? 1.5f : 2.0f));
    else if ((r = diag_check(F, 1048576)) != 0)    code = 16384.0f * (r == 1 ? 1.0f : (r == 2 ? 1.5f : 2.0f));
    else if ((r = diag_check(Ib, 4194304)) != 0)   code = 65536.0f * (r == 1 ? 1.0f : (r == 2 ? 1.5f : 2.0f));
    else if ((r = diag_check(G2, 4194304)) != 0)   code = 262144.0f * (r == 1 ? 1.0f : (r == 2 ? 1.5f : 2.0f));
    if (code != 0.0f) out0[0] = code;
}

// ---------------------------------------------------------------------------
extern "C" void kernel_launch(void* const* d_in, const int* in_sizes, int n_in,
                              void* d_out, int out_size, void* d_ws, size_t ws_size,
                              hipStream_t stream)
{
    const float* src       = (const float*)d_in[0];
    const float* tgt       = (const float*)d_in[1];
    const float* w_enc_in  = (const float*)d_in[2];
    const float* b_enc_in  = (const float*)d_in[3];
    const float* w_dec_in  = (const float*)d_in[4];
    const float* b_dec_in  = (const float*)d_in[5];
    const float* w_map     = (const float*)d_in[6];
    const float* b_map     = (const float*)d_in[7];
    const float* enc_qkv_w = (const float*)d_in[8];
    const float* enc_qkv_b = (const float*)d_in[9];
    const float* enc_out_w = (const float*)d_in[10];
    const float* enc_out_b = (const float*)d_in[11];
    const float* enc_ff1_w = (const float*)d_in[12];
    const float* enc_ff1_b = (const float*)d_in[13];
    const float* enc_ff2_w = (const float*)d_in[14];
    const float* enc_ff2_b = (const float*)d_in[15];
    const float* enc_ln1_g = (const float*)d_in[16];
    const float* enc_ln1_b = (const float*)d_in[17];
    const float* enc_ln2_g = (const float*)d_in[18];
    const float* enc_ln2_b = (const float*)d_in[19];
    const float* enc_fn_g  = (const float*)d_in[20];
    const float* enc_fn_b  = (const float*)d_in[21];
    const float* dec_sa_qkv_w = (const float*)d_in[22];
    const float* dec_sa_qkv_b = (const float*)d_in[23];
    const float* dec_sa_out_w = (const float*)d_in[24];
    const float* dec_sa_out_b = (const float*)d_in[25];
    const float* dec_ca_qkv_w = (const float*)d_in[26];
    const float* dec_ca_qkv_b = (const float*)d_in[27];
    const float* dec_ca_out_w = (const float*)d_in[28];
    const float* dec_ca_out_b = (const float*)d_in[29];
    const float* dec_ff1_w = (const float*)d_in[30];
    const float* dec_ff1_b = (const float*)d_in[31];
    const float* dec_ff2_w = (const float*)d_in[32];
    const float* dec_ff2_b = (const float*)d_in[33];
    const float* dec_ln1_g = (const float*)d_in[34];
    const float* dec_ln1_b = (const float*)d_in[35];
    const float* dec_ln2_g = (const float*)d_in[36];
    const float* dec_ln2_b = (const float*)d_in[37];
    const float* dec_ln3_g = (const float*)d_in[38];
    const float* dec_ln3_b = (const float*)d_in[39];
    const float* dec_fn_g  = (const float*)d_in[40];
    const float* dec_fn_b  = (const float*)d_in[41];
    const float* g1_wl   = (const float*)d_in[42];
    const float* g1_wr   = (const float*)d_in[43];
    const float* g1_bl   = (const float*)d_in[44];
    const float* g1_br   = (const float*)d_in[45];
    const float* g1_att  = (const float*)d_in[46];
    const float* g1_bias = (const float*)d_in[47];
    const float* g2_wl   = (const float*)d_in[48];
    const float* g2_wr   = (const float*)d_in[49];
    const float* g2_bl   = (const float*)d_in[50];
    const float* g2_br   = (const float*)d_in[51];
    const float* g2_att  = (const float*)d_in[52];
    const float* g2_bias = (const float*)d_in[53];
    const int*   edge_index = (const int*)d_in[54];
    const int* esrc = edge_index;
    const int* edst = edge_index + NEDGE;

    // ---- fixed node-chunk C = 128 (footprint ~148 MiB) ----
    const int C = 128;
    const int nchunk = NNODE / C;                 // 4
    const size_t U  = (size_t)C * 32768;          // 4,194,304 floats per unit
    const size_t u2 = U / 2;                      // 2,097,152

    // ---- workspace layout (floats) ----
    float* wsf = (float*)d_ws;
    float* X = wsf;                       // 16,777,216: encoder state -> MEM
    float* Y = X + 16777216;              //  8,388,608: decoder state
    float* F = Y + 8388608;               //  1,048,576: mapped dec out (16384x64)
    float* scr = F + 1048576;             // 12,582,912: 3 units of U
    float* A0 = scr;
    float* A1 = scr + U;
    float* A2 = scr + 2 * U;
    int* ipool = (int*)(scr + 3 * U);
    int* deg = ipool;          // 512
    int* off = deg + 512;      // 516
    int* cur = off + 516;      // 512
    int* eid = cur + 512;      // 16384

    auto gemm = [&](const float* A, int lda, const float* B, int ldb, const float* bias,
                    float* Cc, int ldc, int M, int N, int K, int relu) {
        dim3 grid((unsigned)(N / 64), (unsigned)(M / 64));
        gemm_bias<<<grid, 256, 0, stream>>>(A, lda, B, ldb, bias, Cc, ldc, M, N, K, relu);
    };

    // ---- canary ----
    canary_fill<<<16384, 256, 0, stream>>>((float*)d_out, 16384 * 256);

    // ---- CSR build ----
    zero_ints<<<8, 256, 0, stream>>>(ipool, 512 + 516 + 512);
    count_deg<<<NEDGE / 256, 256, 0, stream>>>(edst, deg);
    scan512<<<1, 512, 0, stream>>>(deg, off);
    fill_eid<<<NEDGE / 256, 256, 0, stream>>>(edst, off, cur, eid);

    // ---- permute inputs to node-major, then plain projections ----
    float* src_nm = A0;                   // 1,048,576 floats
    float* tgt_nm = A0 + 1048576;         // 1,048,576 floats
    permute_in<<<4096, 256, 0, stream>>>(src, src_nm, SLEN, 32, 32768 * 32);
    permute_in<<<4096, 256, 0, stream>>>(tgt, tgt_nm, TLEN, 64, 16384 * 64);
    gemm(src_nm, 32, w_enc_in, 512, b_enc_in, X, 512, 32768, 512, 32, 0);
    gemm(tgt_nm, 64, w_dec_in, 512, b_dec_in, Y, 512, 16384, 512, 64, 0);
    add_posenc<<<(32768 * 512) / 256, 256, 0, stream>>>(X, SLEN, 32768 * 512);
    add_posenc<<<(16384 * 512) / 256, 256, 0, stream>>>(Y, TLEN, 16384 * 512);

    // ================= encoder (per node-chunk, all layers) =================
    for (int c = 0; c < nchunk; ++c) {
        float* Xc = X + (size_t)c * U;
        const int rows = C * 64;   // 8192
        for (int i = 0; i < NLAYER; ++i) {
            const float* qkvW = enc_qkv_w + (size_t)i * 512 * 1536;
            const float* qkvB = enc_qkv_b + (size_t)i * 1536;
            gemm(Xc, 512, qkvW,        1536, qkvB,        A0, 512, rows, 512, 512, 0);
            gemm(Xc, 512, qkvW + 512,  1536, qkvB + 512,  A1, 512, rows, 512, 512, 0);
            gemm(Xc, 512, qkvW + 1024, 1536, qkvB + 1024, A2, 512, rows, 512, 512, 0);
            attn_kernel<64, 64, false><<<C * 8, 64, 0, stream>>>(A0, 512, A1, 512, A2, 512, A0, 512);
            gemm(A0, 512, enc_out_w + (size_t)i * 512 * 512, 512, enc_out_b + (size_t)i * 512,
                 A1, 512, rows, 512, 512, 0);
            ln_kernel<<<rows / 4, 256, 0, stream>>>(Xc, A1,
                 enc_ln1_g + (size_t)i * 512, enc_ln1_b + (size_t)i * 512, Xc, rows);
            const int Rsc = C * 16;   // 2048 rows per FFN sub-chunk
            for (int s = 0; s < 4; ++s) {
                gemm(Xc + (size_t)s * Rsc * 512, 512, enc_ff1_w + (size_t)i * 512 * 2048, 2048,
                     enc_ff1_b + (size_t)i * 2048, A2, 2048, Rsc, 2048, 512, 1);
                gemm(A2, 2048, enc_ff2_w + (size_t)i * 2048 * 512, 512,
                     enc_ff2_b + (size_t)i * 512, A0 + (size_t)s * Rsc * 512, 512, Rsc, 512, 2048, 0);
            }
            ln_kernel<<<rows / 4, 256, 0, stream>>>(Xc, A0,
                 enc_ln2_g + (size_t)i * 512, enc_ln2_b + (size_t)i * 512, Xc, rows);
        }
        ln_kernel<<<rows / 4, 256, 0, stream>>>(Xc, nullptr, enc_fn_g, enc_fn_b, Xc, rows);
    }
    // X is now MEM (node-major)

    // ================= decoder (per node-chunk, all layers) =================
    for (int c = 0; c < nchunk; ++c) {
        float* Yc = Y + (size_t)c * u2;
        float* MEMc = X + (size_t)c * U;
        const int rows = C * 32;   // 4096
        for (int i = 0; i < NLAYER; ++i) {
            // causal self-attention
            const float* saW = dec_sa_qkv_w + (size_t)i * 512 * 1536;
            const float* saB = dec_sa_qkv_b + (size_t)i * 1536;
            float* sq = A0; float* sk = A0 + u2; float* sv = A1; float* so = A1 + u2;
            gemm(Yc, 512, saW,        1536, saB,        sq, 512, rows, 512, 512, 0);
            gemm(Yc, 512, saW + 512,  1536, saB + 512,  sk, 512, rows, 512, 512, 0);
            gemm(Yc, 512, saW + 1024, 1536, saB + 1024, sv, 512, rows, 512, 512, 0);
            attn_kernel<32, 32, true><<<C * 8, 64, 0, stream>>>(sq, 512, sk, 512, sv, 512, sq, 512);
            gemm(sq, 512, dec_sa_out_w + (size_t)i * 512 * 512, 512, dec_sa_out_b + (size_t)i * 512,
                 so, 512, rows, 512, 512, 0);
            ln_kernel<<<rows / 4, 256, 0, stream>>>(Yc, so,
                 dec_ln1_g + (size_t)i * 512, dec_ln1_b + (size_t)i * 512, Yc, rows);
            // cross-attention
            const float* caW = dec_ca_qkv_w + (size_t)i * 512 * 1536;
            const float* caB = dec_ca_qkv_b + (size_t)i * 1536;
            gemm(Yc,   512, caW,        1536, caB,        A0, 512, rows,   512, 512, 0);
            gemm(MEMc, 512, caW + 512,  1536, caB + 512,  A1, 512, C * 64, 512, 512, 0);
            gemm(MEMc, 512, caW + 1024, 1536, caB + 1024, A2, 512, C * 64, 512, 512, 0);
            attn_kernel<32, 64, false><<<C * 8, 64, 0, stream>>>(A0, 512, A1, 512, A2, 512, A0, 512);
            gemm(A0, 512, dec_ca_out_w + (size_t)i * 512 * 512, 512, dec_ca_out_b + (size_t)i * 512,
                 A0 + u2, 512, rows, 512, 512, 0);
            ln_kernel<<<rows / 4, 256, 0, stream>>>(Yc, A0 + u2,
                 dec_ln2_g + (size_t)i * 512, dec_ln2_b + (size_t)i * 512, Yc, rows);
            // FFN
            const int Rd = C * 16;   // 2048
            for (int s = 0; s < 2; ++s) {
                gemm(Yc + (size_t)s * Rd * 512, 512, dec_ff1_w + (size_t)i * 512 * 2048, 2048,
                     dec_ff1_b + (size_t)i * 2048, A0, 2048, Rd, 2048, 512, 1);
                gemm(A0, 2048, dec_ff2_w + (size_t)i * 2048 * 512, 512,
                     dec_ff2_b + (size_t)i * 512, A1 + (size_t)s * Rd * 512, 512, Rd, 512, 2048, 0);
            }
            ln_kernel<<<rows / 4, 256, 0, stream>>>(Yc, A1,
                 dec_ln3_g + (size_t)i * 512, dec_ln3_b + (size_t)i * 512, Yc, rows);
        }
        ln_kernel<<<rows / 4, 256, 0, stream>>>(Yc, nullptr, dec_fn_g, dec_fn_b, Yc, rows);
    }

    // map to FEAT=64 (node-major rows n*32+t)
    gemm(Y, 512, w_map, 64, b_map, F, 64, 16384, 64, 512, 0);

    // ================= spatial GATv2 =================
    float* G  = scr;                // 4,194,304
    float* Hb = scr + 4194304;
    float* Ib = scr + 8388608;
    gemm(F, 64, g1_wl, 256, g1_bl, G,  256, 16384, 256, 64, 0);
    gemm(F, 64, g1_wr, 256, g1_br, Hb, 256, 16384, 256, 64, 0);
    gatv2_kernel<false><<<16384, 256, 0, stream>>>(G, Hb, g1_att, g1_bias, off, eid, esrc, Ib, nullptr);
    gemm(Ib, 256, g2_wl, 256, g2_bl, G,  256, 16384, 256, 256, 0);
    gemm(Ib, 256, g2_wr, 256, g2_br, Hb, 256, 16384, 256, 256, 0);
    gatv2_kernel<true><<<16384, 256, 0, stream>>>(G, Hb, g2_att, g2_bias, off, eid, esrc,
                                                  nullptr, (float*)d_out);

    // ---- diagnostics (writes d_out[0] only on anomaly) ----
    diag_kernel<<<1, 64, 0, stream>>>(X, Y, F, Ib, G, (float*)d_out);
}

// Round 5
// 20036.485 us; speedup vs baseline: 1.5514x; 1.5514x over previous
//
#include <hip/hip_runtime.h>
#include <hip/hip_bf16.h>

// Problem constants
#define NHEAD 8
#define SLEN 64
#define TLEN 32
#define NNODE 512
#define NEDGE 16384
#define NLAYER 4

typedef __attribute__((ext_vector_type(8))) __bf16 bf16x8;
typedef __attribute__((ext_vector_type(4))) __bf16 bf16x4;
typedef __attribute__((ext_vector_type(4))) float  f32x4;

// ---------------------------------------------------------------------------
// bf16 MFMA GEMM: C[M,N] = A[M,K] @ B[K,N] + bias[N], optional relu.
// A,B fp32 in HBM, converted to bf16 during LDS staging. Accum fp32 (MFMA).
// BM=BN=128, BK=64, 256 threads = 4 waves (2x2), wave tile 64x64 (4x4 frags
// of 16x16x32). Requires M%128==0, N%128==0, K%64==0.
// ---------------------------------------------------------------------------
__global__ __launch_bounds__(256) void gemm_mfma(
    const float* __restrict__ A, int lda,
    const float* __restrict__ B, int ldb,
    const float* __restrict__ bias,
    float* __restrict__ C, int ldc,
    int M, int N, int K, int relu)
{
    __shared__ __bf16 As[128][80];   // [row][k], stride 160B (16B-aligned)
    __shared__ __bf16 Bs[128][80];   // [col][k] (transposed during staging)
    const int tid  = threadIdx.x;
    const int wid  = tid >> 6;
    const int lane = tid & 63;
    const int wr = wid >> 1, wc = wid & 1;
    const int m0 = blockIdx.y * 128, n0 = blockIdx.x * 128;

    // staging indices
    const int a_k4 = (tid & 15) * 4;   // A: float4 col offset 0..60
    const int a_r  = tid >> 4;         // A: base row 0..15 (8 rows step 16)
    const int b_nb = (tid & 15) * 8;   // B: 8-col segment 0..120
    const int b_kb = (tid >> 4) * 4;   // B: 4-row k group 0..60

    // fragment indices
    const int lr = lane & 15;          // frag row (A) / col (B)
    const int kg = (lane >> 4) * 8;    // k-offset group {0,8,16,24}

    f32x4 acc[4][4];
    #pragma unroll
    for (int m = 0; m < 4; ++m)
        #pragma unroll
        for (int n = 0; n < 4; ++n)
            acc[m][n] = (f32x4){0.0f, 0.0f, 0.0f, 0.0f};

    for (int k0 = 0; k0 < K; k0 += 64) {
        // ---- stage A (128x64): 8 rows x one float4 per thread ----
        #pragma unroll
        for (int i = 0; i < 8; ++i) {
            const int row = a_r + i * 16;
            const float4 v = *reinterpret_cast<const float4*>(
                &A[(size_t)(m0 + row) * lda + k0 + a_k4]);
            bf16x4 w;
            w[0] = (__bf16)v.x; w[1] = (__bf16)v.y;
            w[2] = (__bf16)v.z; w[3] = (__bf16)v.w;
            *reinterpret_cast<bf16x4*>(&As[row][a_k4]) = w;
        }
        // ---- stage B (64x128) transposed: 4k x 8n block per thread ----
        __bf16 bv[4][8];
        #pragma unroll
        for (int dk = 0; dk < 4; ++dk) {
            const size_t roff = (size_t)(k0 + b_kb + dk) * ldb + n0 + b_nb;
            const float4 u0 = *reinterpret_cast<const float4*>(&B[roff]);
            const float4 u1 = *reinterpret_cast<const float4*>(&B[roff + 4]);
            bv[dk][0] = (__bf16)u0.x; bv[dk][1] = (__bf16)u0.y;
            bv[dk][2] = (__bf16)u0.z; bv[dk][3] = (__bf16)u0.w;
            bv[dk][4] = (__bf16)u1.x; bv[dk][5] = (__bf16)u1.y;
            bv[dk][6] = (__bf16)u1.z; bv[dk][7] = (__bf16)u1.w;
        }
        #pragma unroll
        for (int dn = 0; dn < 8; ++dn) {
            bf16x4 w;
            w[0] = bv[0][dn]; w[1] = bv[1][dn]; w[2] = bv[2][dn]; w[3] = bv[3][dn];
            *reinterpret_cast<bf16x4*>(&Bs[b_nb + dn][b_kb]) = w;
        }
        __syncthreads();
        // ---- MFMA: 2 k-slices of 32, 4x4 fragment grid per wave ----
        #pragma unroll
        for (int kk = 0; kk < 64; kk += 32) {
            bf16x8 fa[4], fb[4];
            #pragma unroll
            for (int m = 0; m < 4; ++m)
                fa[m] = *reinterpret_cast<const bf16x8*>(&As[wr * 64 + m * 16 + lr][kk + kg]);
            #pragma unroll
            for (int n = 0; n < 4; ++n)
                fb[n] = *reinterpret_cast<const bf16x8*>(&Bs[wc * 64 + n * 16 + lr][kk + kg]);
            #pragma unroll
            for (int m = 0; m < 4; ++m)
                #pragma unroll
                for (int n = 0; n < 4; ++n)
                    acc[m][n] = __builtin_amdgcn_mfma_f32_16x16x32_bf16(
                        fa[m], fb[n], acc[m][n], 0, 0, 0);
        }
        __syncthreads();
    }

    // ---- epilogue: C/D layout col=lane&15, row=(lane>>4)*4+reg ----
    const int cr = (lane >> 4) * 4;
    const int cc = lane & 15;
    #pragma unroll
    for (int n = 0; n < 4; ++n) {
        const int gcol = n0 + wc * 64 + n * 16 + cc;
        const float bb = bias[gcol];
        #pragma unroll
        for (int m = 0; m < 4; ++m) {
            #pragma unroll
            for (int j = 0; j < 4; ++j) {
                const int grow = m0 + wr * 64 + m * 16 + cr + j;
                float v = acc[m][n][j] + bb;
                if (relu) v = fmaxf(v, 0.0f);
                C[(size_t)grow * ldc + gcol] = v;
            }
        }
    }
}

// ---------------------------------------------------------------------------
// fp32 GEMM (kept for small/odd shapes: src/tgt proj, w_map, GAT g1/g2)
// ---------------------------------------------------------------------------
__global__ __launch_bounds__(256) void gemm_bias(
    const float* __restrict__ A, int lda,
    const float* __restrict__ B, int ldb,
    const float* __restrict__ bias,
    float* __restrict__ C, int ldc,
    int M, int N, int K, int relu)
{
    __shared__ float As[16][68];
    __shared__ float Bs[16][68];
    const int tid = threadIdx.x;
    const int tx = tid & 15, ty = tid >> 4;
    const int m0 = blockIdx.y * 64, n0 = blockIdx.x * 64;
    const int liA_m = tid >> 2;
    const int liA_k = (tid & 3) * 4;
    const int liB_n = (tid & 15) * 4;
    const int liB_k = tid >> 4;
    float acc[4][4] = {};
    for (int k0 = 0; k0 < K; k0 += 16) {
        float4 av = *reinterpret_cast<const float4*>(&A[(size_t)(m0 + liA_m) * lda + k0 + liA_k]);
        float4 bv = *reinterpret_cast<const float4*>(&B[(size_t)(k0 + liB_k) * ldb + n0 + liB_n]);
        As[liA_k + 0][liA_m] = av.x;
        As[liA_k + 1][liA_m] = av.y;
        As[liA_k + 2][liA_m] = av.z;
        As[liA_k + 3][liA_m] = av.w;
        *reinterpret_cast<float4*>(&Bs[liB_k][liB_n]) = bv;
        __syncthreads();
        #pragma unroll
        for (int kk = 0; kk < 16; ++kk) {
            float4 a4 = *reinterpret_cast<const float4*>(&As[kk][ty * 4]);
            float4 b4 = *reinterpret_cast<const float4*>(&Bs[kk][tx * 4]);
            float a[4] = {a4.x, a4.y, a4.z, a4.w};
            float b[4] = {b4.x, b4.y, b4.z, b4.w};
            #pragma unroll
            for (int i = 0; i < 4; ++i)
                #pragma unroll
                for (int j = 0; j < 4; ++j)
                    acc[i][j] += a[i] * b[j];
        }
        __syncthreads();
    }
    #pragma unroll
    for (int i = 0; i < 4; ++i) {
        const int m = m0 + ty * 4 + i;
        #pragma unroll
        for (int j = 0; j < 4; ++j) {
            const int n = n0 + tx * 4 + j;
            float v = acc[i][j] + bias[n];
            if (relu) v = fmaxf(v, 0.0f);
            C[(size_t)m * ldc + n] = v;
        }
    }
}

// ---------------------------------------------------------------------------
// Permute seq-first (L,512,CH) -> node-major (512,L,CH). Elementwise gather.
// ---------------------------------------------------------------------------
__global__ __launch_bounds__(256) void permute_in(
    const float* __restrict__ in, float* __restrict__ out, int L, int CH, int total)
{
    const int idx = blockIdx.x * 256 + threadIdx.x;
    if (idx >= total) return;
    const int c = idx % CH;
    const int r = idx / CH;       // r = l*512 + n
    const int n = r & 511;
    const int l = r >> 9;
    out[((size_t)n * L + l) * CH + c] = in[idx];
}

// ---------------------------------------------------------------------------
// Fused MHA, node-major: block = (n_local, h). One wave, online softmax.
// ---------------------------------------------------------------------------
template<int LQ, int LK, bool CAUSAL>
__global__ __launch_bounds__(64) void attn_kernel(
    const float* __restrict__ Q, int ldq,
    const float* __restrict__ Kp, int ldk,
    const float* __restrict__ Vp, int ldv,
    float* __restrict__ O, int ldo)
{
    __shared__ float qs[LQ][68];
    __shared__ float ks[LK][68];
    __shared__ float vs[LK][68];
    const int n = blockIdx.x >> 3;
    const int h = blockIdx.x & 7;
    const int lane = threadIdx.x;
    const int col = h * 64 + lane;
    for (int r = 0; r < LQ; ++r) qs[r][lane] = Q[(size_t)(n * LQ + r) * ldq + col];
    for (int r = 0; r < LK; ++r) ks[r][lane] = Kp[(size_t)(n * LK + r) * ldk + col];
    for (int r = 0; r < LK; ++r) vs[r][lane] = Vp[(size_t)(n * LK + r) * ldv + col];
    __syncthreads();
    float o[64];
    if (lane < LQ) {
        float qr[64];
        #pragma unroll
        for (int j = 0; j < 64; ++j) { qr[j] = qs[lane][j]; o[j] = 0.0f; }
        float m = -1e30f, l = 0.0f;
        const int kend = CAUSAL ? (lane + 1) : LK;
        for (int kk = 0; kk < kend; ++kk) {
            float s = 0.0f;
            #pragma unroll
            for (int j = 0; j < 16; ++j) {
                float4 kv = *reinterpret_cast<const float4*>(&ks[kk][j * 4]);
                s += qr[4*j+0]*kv.x + qr[4*j+1]*kv.y + qr[4*j+2]*kv.z + qr[4*j+3]*kv.w;
            }
            s *= 0.125f;
            const float mn = fmaxf(m, s);
            const float sc = expf(m - mn);
            const float p  = expf(s - mn);
            l = l * sc + p;
            #pragma unroll
            for (int j = 0; j < 16; ++j) {
                float4 vv = *reinterpret_cast<const float4*>(&vs[kk][j * 4]);
                o[4*j+0] = o[4*j+0] * sc + p * vv.x;
                o[4*j+1] = o[4*j+1] * sc + p * vv.y;
                o[4*j+2] = o[4*j+2] * sc + p * vv.z;
                o[4*j+3] = o[4*j+3] * sc + p * vv.w;
            }
            m = mn;
        }
        const float inv = 1.0f / l;
        #pragma unroll
        for (int j = 0; j < 64; ++j) o[j] *= inv;
    }
    __syncthreads();
    if (lane < LQ) {
        #pragma unroll
        for (int j = 0; j < 64; ++j) qs[lane][j] = o[j];
    }
    __syncthreads();
    for (int r = 0; r < LQ; ++r) O[(size_t)(n * LQ + r) * ldo + col] = qs[r][lane];
}

// ---------------------------------------------------------------------------
// LayerNorm over last dim (512): out = LN(x [+ res]) * g + b. Wave per row.
// ---------------------------------------------------------------------------
__global__ __launch_bounds__(256) void ln_kernel(
    const float* __restrict__ X, const float* __restrict__ R,
    const float* __restrict__ g, const float* __restrict__ b,
    float* __restrict__ out, int ntok)
{
    const int wid = threadIdx.x >> 6, lane = threadIdx.x & 63;
    const int row = blockIdx.x * 4 + wid;
    if (row >= ntok) return;
    const size_t base = (size_t)row * 512;
    float v[8];
    float s = 0.0f;
    const bool hasR = (R != nullptr);
    #pragma unroll
    for (int j = 0; j < 8; ++j) {
        float t = X[base + j * 64 + lane];
        if (hasR) t += R[base + j * 64 + lane];
        v[j] = t; s += t;
    }
    #pragma unroll
    for (int d = 32; d >= 1; d >>= 1) s += __shfl_xor(s, d, 64);
    const float mean = s * (1.0f / 512.0f);
    float vs = 0.0f;
    #pragma unroll
    for (int j = 0; j < 8; ++j) { const float d = v[j] - mean; vs += d * d; }
    #pragma unroll
    for (int d = 32; d >= 1; d >>= 1) vs += __shfl_xor(vs, d, 64);
    const float rstd = rsqrtf(vs * (1.0f / 512.0f) + 1e-5f);
    #pragma unroll
    for (int j = 0; j < 8; ++j) {
        const int c = j * 64 + lane;
        out[base + c] = (v[j] - mean) * rstd * g[c] + b[c];
    }
}

// ---------------------------------------------------------------------------
// Sinusoidal positional encoding add, node-major (row = n*L + l)
// ---------------------------------------------------------------------------
__global__ __launch_bounds__(256) void add_posenc(float* __restrict__ x, int L, int total)
{
    const int idx = blockIdx.x * 256 + threadIdx.x;
    if (idx >= total) return;
    const int d = idx & 511;
    const int row = idx >> 9;
    const int l = row % L;
    const int i2 = d & ~1;
    const float freq = expf(-9.210340371976184f * (float)i2 / 512.0f);
    const float a = (float)l * freq;
    x[idx] += (d & 1) ? cosf(a) : sinf(a);
}

// ---------------------------------------------------------------------------
// CSR build for GATv2 (incoming edges per dst node)
// ---------------------------------------------------------------------------
__global__ void zero_ints(int* __restrict__ p, int n)
{
    const int i = blockIdx.x * 256 + threadIdx.x;
    if (i < n) p[i] = 0;
}

__global__ void count_deg(const int* __restrict__ edst, int* __restrict__ deg)
{
    const int e = blockIdx.x * 256 + threadIdx.x;
    if (e < NEDGE) atomicAdd(&deg[edst[e]], 1);
}

__global__ void scan512(const int* __restrict__ deg, int* __restrict__ off)
{
    __shared__ int s[512];
    const int tid = threadIdx.x;
    s[tid] = deg[tid];
    __syncthreads();
    for (int d = 1; d < 512; d <<= 1) {
        const int t = (tid >= d) ? s[tid - d] : 0;
        __syncthreads();
        s[tid] += t;
        __syncthreads();
    }
    off[tid + 1] = s[tid];
    if (tid == 0) off[0] = 0;
}

__global__ void fill_eid(const int* __restrict__ edst, const int* __restrict__ off,
                         int* __restrict__ cur, int* __restrict__ eid)
{
    const int e = blockIdx.x * 256 + threadIdx.x;
    if (e < NEDGE) {
        const int d = edst[e];
        const int pos = off[d] + atomicAdd(&cur[d], 1);
        eid[pos] = e;
    }
}

// ---------------------------------------------------------------------------
// GATv2 layer: block per (t, dst). 256 threads = 8 heads x 32 ch.
// ---------------------------------------------------------------------------
template<bool FINAL>
__global__ __launch_bounds__(256) void gatv2_kernel(
    const float* __restrict__ xl, const float* __restrict__ xr,
    const float* __restrict__ att, const float* __restrict__ bias,
    const int* __restrict__ off, const int* __restrict__ eid,
    const int* __restrict__ esrc,
    float* __restrict__ outf, float* __restrict__ outd)
{
    const int blk = blockIdx.x;       // t*NNODE + i
    const int i = blk & (NNODE - 1);
    const int t = blk >> 9;
    const int tid = threadIdx.x;
    const float xrv = xr[((size_t)i * TLEN + t) * 256 + tid];
    const float av = att[tid];
    const int e0 = off[i], e1 = off[i + 1];
    float m = -1e30f, den = 0.0f, acc = 0.0f;
    for (int idx = e0; idx < e1; ++idx) {
        const int e = eid[idx];
        const int s = esrc[e];
        const float xlv = xl[((size_t)s * TLEN + t) * 256 + tid];
        float z = xlv + xrv;
        z = (z > 0.0f) ? z : 0.2f * z;
        float w = z * av;
        #pragma unroll
        for (int d = 16; d >= 1; d >>= 1) w += __shfl_xor(w, d, 32);
        const float mn = fmaxf(m, w);
        const float sc = expf(m - mn);
        const float p  = expf(w - mn);
        den = den * sc + p;
        acc = acc * sc + p * xlv;
        m = mn;
    }
    float o = (den > 0.0f) ? acc / den : 0.0f;
    o += bias[tid];
    if (FINAL) {
        o = fmaxf(o, 0.0f);
        outd[(size_t)blk * 256 + tid] = o;
    } else {
        outf[((size_t)i * TLEN + t) * 256 + tid] = o;
    }
}

__global__ __launch_bounds__(256) void canary_fill(float* __restrict__ out, int total)
{
    const int idx = blockIdx.x * 256 + threadIdx.x;
    if (idx < total) out[idx] = 336.0f;
}

__device__ int diag_check(const float* p, size_t n)
{
    bool nan = false, nz = false; float mx = 0.0f;
    const size_t stride = n / 256;
    for (int i = 0; i < 256; ++i) {
        const float v = p[(size_t)i * stride];
        if (v != v || fabsf(v) > 1e30f) nan = true;
        if (v != 0.0f) nz = true;
        const float a = fabsf(v);
        if (a > mx) mx = a;
    }
    if (nan) return 1;
    if (!nz) return 2;
    if (mx > 1e4f) return 3;
    return 0;
}

__global__ void diag_kernel(const float* __restrict__ MEM, const float* __restrict__ Y,
                            const float* __restrict__ F, const float* __restrict__ Ib,
                            const float* __restrict__ G2, float* __restrict__ out0)
{
    if (threadIdx.x != 0 || blockIdx.x != 0) return;
    float code = 0.0f;
    int r;
    if ((r = diag_check(MEM, 16777216)) != 0)      code = 1024.0f * (r == 1 ? 1.0f : (r == 2 ? 1.5f : 2.0f));
    else if ((r = diag_check(Y, 8388608)) != 0)    code = 4096.0f * (r == 1 ? 1.0f : (r == 2 ? 1.5f : 2.0f));
    else if ((r = diag_check(F, 1048576)) != 0)    code = 16384.0f * (r == 1 ? 1.0f : (r == 2 ? 1.5f : 2.0f));
    else if ((r = diag_check(Ib, 4194304)) != 0)   code = 65536.0f * (r == 1 ? 1.0f : (r == 2 ? 1.5f : 2.0f));
    else if ((r = diag_check(G2, 4194304)) != 0)   code = 262144.0f * (r == 1 ? 1.0f : (r == 2 ? 1.5f : 2.0f));
    if (code != 0.0f) out0[0] = code;
}

// ---------------------------------------------------------------------------
extern "C" void kernel_launch(void* const* d_in, const int* in_sizes, int n_in,
                              void* d_out, int out_size, void* d_ws, size_t ws_size,
                              hipStream_t stream)
{
    const float* src       = (const float*)d_in[0];
    const float* tgt       = (const float*)d_in[1];
    const float* w_enc_in  = (const float*)d_in[2];
    const float* b_enc_in  = (const float*)d_in[3];
    const float* w_dec_in  = (const float*)d_in[4];
    const float* b_dec_in  = (const float*)d_in[5];
    const float* w_map     = (const float*)d_in[6];
    const float* b_map     = (const float*)d_in[7];
    const float* enc_qkv_w = (const float*)d_in[8];
    const float* enc_qkv_b = (const float*)d_in[9];
    const float* enc_out_w = (const float*)d_in[10];
    const float* enc_out_b = (const float*)d_in[11];
    const float* enc_ff1_w = (const float*)d_in[12];
    const float* enc_ff1_b = (const float*)d_in[13];
    const float* enc_ff2_w = (const float*)d_in[14];
    const float* enc_ff2_b = (const float*)d_in[15];
    const float* enc_ln1_g = (const float*)d_in[16];
    const float* enc_ln1_b = (const float*)d_in[17];
    const float* enc_ln2_g = (const float*)d_in[18];
    const float* enc_ln2_b = (const float*)d_in[19];
    const float* enc_fn_g  = (const float*)d_in[20];
    const float* enc_fn_b  = (const float*)d_in[21];
    const float* dec_sa_qkv_w = (const float*)d_in[22];
    const float* dec_sa_qkv_b = (const float*)d_in[23];
    const float* dec_sa_out_w = (const float*)d_in[24];
    const float* dec_sa_out_b = (const float*)d_in[25];
    const float* dec_ca_qkv_w = (const float*)d_in[26];
    const float* dec_ca_qkv_b = (const float*)d_in[27];
    const float* dec_ca_out_w = (const float*)d_in[28];
    const float* dec_ca_out_b = (const float*)d_in[29];
    const float* dec_ff1_w = (const float*)d_in[30];
    const float* dec_ff1_b = (const float*)d_in[31];
    const float* dec_ff2_w = (const float*)d_in[32];
    const float* dec_ff2_b = (const float*)d_in[33];
    const float* dec_ln1_g = (const float*)d_in[34];
    const float* dec_ln1_b = (const float*)d_in[35];
    const float* dec_ln2_g = (const float*)d_in[36];
    const float* dec_ln2_b = (const float*)d_in[37];
    const float* dec_ln3_g = (const float*)d_in[38];
    const float* dec_ln3_b = (const float*)d_in[39];
    const float* dec_fn_g  = (const float*)d_in[40];
    const float* dec_fn_b  = (const float*)d_in[41];
    const float* g1_wl   = (const float*)d_in[42];
    const float* g1_wr   = (const float*)d_in[43];
    const float* g1_bl   = (const float*)d_in[44];
    const float* g1_br   = (const float*)d_in[45];
    const float* g1_att  = (const float*)d_in[46];
    const float* g1_bias = (const float*)d_in[47];
    const float* g2_wl   = (const float*)d_in[48];
    const float* g2_wr   = (const float*)d_in[49];
    const float* g2_bl   = (const float*)d_in[50];
    const float* g2_br   = (const float*)d_in[51];
    const float* g2_att  = (const float*)d_in[52];
    const float* g2_bias = (const float*)d_in[53];
    const int*   edge_index = (const int*)d_in[54];
    const int* esrc = edge_index;
    const int* edst = edge_index + NEDGE;

    const int C = 128;
    const int nchunk = NNODE / C;                 // 4
    const size_t U  = (size_t)C * 32768;          // 4,194,304 floats
    const size_t u2 = U / 2;                      // 2,097,152

    float* wsf = (float*)d_ws;
    float* X = wsf;                       // 16,777,216
    float* Y = X + 16777216;              //  8,388,608
    float* F = Y + 8388608;               //  1,048,576
    float* scr = F + 1048576;             // 12,582,912
    float* A0 = scr;
    float* A1 = scr + U;
    float* A2 = scr + 2 * U;
    int* ipool = (int*)(scr + 3 * U);
    int* deg = ipool;
    int* off = deg + 512;
    int* cur = off + 516;
    int* eid = cur + 512;

    auto gemm = [&](const float* A, int lda, const float* B, int ldb, const float* bias,
                    float* Cc, int ldc, int M, int N, int K, int relu) {
        dim3 grid((unsigned)(N / 64), (unsigned)(M / 64));
        gemm_bias<<<grid, 256, 0, stream>>>(A, lda, B, ldb, bias, Cc, ldc, M, N, K, relu);
    };
    auto gemmB = [&](const float* A, int lda, const float* B, int ldb, const float* bias,
                     float* Cc, int ldc, int M, int N, int K, int relu) {
        dim3 grid((unsigned)(N / 128), (unsigned)(M / 128));
        gemm_mfma<<<grid, 256, 0, stream>>>(A, lda, B, ldb, bias, Cc, ldc, M, N, K, relu);
    };

    canary_fill<<<16384, 256, 0, stream>>>((float*)d_out, 16384 * 256);

    zero_ints<<<8, 256, 0, stream>>>(ipool, 512 + 516 + 512);
    count_deg<<<NEDGE / 256, 256, 0, stream>>>(edst, deg);
    scan512<<<1, 512, 0, stream>>>(deg, off);
    fill_eid<<<NEDGE / 256, 256, 0, stream>>>(edst, off, cur, eid);

    // ---- permute inputs to node-major, then plain fp32 projections ----
    float* src_nm = A0;
    float* tgt_nm = A0 + 1048576;
    permute_in<<<4096, 256, 0, stream>>>(src, src_nm, SLEN, 32, 32768 * 32);
    permute_in<<<4096, 256, 0, stream>>>(tgt, tgt_nm, TLEN, 64, 16384 * 64);
    gemm(src_nm, 32, w_enc_in, 512, b_enc_in, X, 512, 32768, 512, 32, 0);
    gemm(tgt_nm, 64, w_dec_in, 512, b_dec_in, Y, 512, 16384, 512, 64, 0);
    add_posenc<<<(32768 * 512) / 256, 256, 0, stream>>>(X, SLEN, 32768 * 512);
    add_posenc<<<(16384 * 512) / 256, 256, 0, stream>>>(Y, TLEN, 16384 * 512);

    // ================= encoder =================
    for (int c = 0; c < nchunk; ++c) {
        float* Xc = X + (size_t)c * U;
        const int rows = C * 64;   // 8192
        for (int i = 0; i < NLAYER; ++i) {
            const float* qkvW = enc_qkv_w + (size_t)i * 512 * 1536;
            const float* qkvB = enc_qkv_b + (size_t)i * 1536;
            gemmB(Xc, 512, qkvW,        1536, qkvB,        A0, 512, rows, 512, 512, 0);
            gemmB(Xc, 512, qkvW + 512,  1536, qkvB + 512,  A1, 512, rows, 512, 512, 0);
            gemmB(Xc, 512, qkvW + 1024, 1536, qkvB + 1024, A2, 512, rows, 512, 512, 0);
            attn_kernel<64, 64, false><<<C * 8, 64, 0, stream>>>(A0, 512, A1, 512, A2, 512, A0, 512);
            gemmB(A0, 512, enc_out_w + (size_t)i * 512 * 512, 512, enc_out_b + (size_t)i * 512,
                  A1, 512, rows, 512, 512, 0);
            ln_kernel<<<rows / 4, 256, 0, stream>>>(Xc, A1,
                 enc_ln1_g + (size_t)i * 512, enc_ln1_b + (size_t)i * 512, Xc, rows);
            const int Rsc = C * 16;   // 2048
            for (int s = 0; s < 4; ++s) {
                gemmB(Xc + (size_t)s * Rsc * 512, 512, enc_ff1_w + (size_t)i * 512 * 2048, 2048,
                      enc_ff1_b + (size_t)i * 2048, A2, 2048, Rsc, 2048, 512, 1);
                gemmB(A2, 2048, enc_ff2_w + (size_t)i * 2048 * 512, 512,
                      enc_ff2_b + (size_t)i * 512, A0 + (size_t)s * Rsc * 512, 512, Rsc, 512, 2048, 0);
            }
            ln_kernel<<<rows / 4, 256, 0, stream>>>(Xc, A0,
                 enc_ln2_g + (size_t)i * 512, enc_ln2_b + (size_t)i * 512, Xc, rows);
        }
        ln_kernel<<<rows / 4, 256, 0, stream>>>(Xc, nullptr, enc_fn_g, enc_fn_b, Xc, rows);
    }

    // ================= decoder =================
    for (int c = 0; c < nchunk; ++c) {
        float* Yc = Y + (size_t)c * u2;
        float* MEMc = X + (size_t)c * U;
        const int rows = C * 32;   // 4096
        for (int i = 0; i < NLAYER; ++i) {
            const float* saW = dec_sa_qkv_w + (size_t)i * 512 * 1536;
            const float* saB = dec_sa_qkv_b + (size_t)i * 1536;
            float* sq = A0; float* sk = A0 + u2; float* sv = A1; float* so = A1 + u2;
            gemmB(Yc, 512, saW,        1536, saB,        sq, 512, rows, 512, 512, 0);
            gemmB(Yc, 512, saW + 512,  1536, saB + 512,  sk, 512, rows, 512, 512, 0);
            gemmB(Yc, 512, saW + 1024, 1536, saB + 1024, sv, 512, rows, 512, 512, 0);
            attn_kernel<32, 32, true><<<C * 8, 64, 0, stream>>>(sq, 512, sk, 512, sv, 512, sq, 512);
            gemmB(sq, 512, dec_sa_out_w + (size_t)i * 512 * 512, 512, dec_sa_out_b + (size_t)i * 512,
                  so, 512, rows, 512, 512, 0);
            ln_kernel<<<rows / 4, 256, 0, stream>>>(Yc, so,
                 dec_ln1_g + (size_t)i * 512, dec_ln1_b + (size_t)i * 512, Yc, rows);
            const float* caW = dec_ca_qkv_w + (size_t)i * 512 * 1536;
            const float* caB = dec_ca_qkv_b + (size_t)i * 1536;
            gemmB(Yc,   512, caW,        1536, caB,        A0, 512, rows,   512, 512, 0);
            gemmB(MEMc, 512, caW + 512,  1536, caB + 512,  A1, 512, C * 64, 512, 512, 0);
            gemmB(MEMc, 512, caW + 1024, 1536, caB + 1024, A2, 512, C * 64, 512, 512, 0);
            attn_kernel<32, 64, false><<<C * 8, 64, 0, stream>>>(A0, 512, A1, 512, A2, 512, A0, 512);
            gemmB(A0, 512, dec_ca_out_w + (size_t)i * 512 * 512, 512, dec_ca_out_b + (size_t)i * 512,
                  A0 + u2, 512, rows, 512, 512, 0);
            ln_kernel<<<rows / 4, 256, 0, stream>>>(Yc, A0 + u2,
                 dec_ln2_g + (size_t)i * 512, dec_ln2_b + (size_t)i * 512, Yc, rows);
            const int Rd = C * 16;   // 2048
            for (int s = 0; s < 2; ++s) {
                gemmB(Yc + (size_t)s * Rd * 512, 512, dec_ff1_w + (size_t)i * 512 * 2048, 2048,
                      dec_ff1_b + (size_t)i * 2048, A0, 2048, Rd, 2048, 512, 1);
                gemmB(A0, 2048, dec_ff2_w + (size_t)i * 2048 * 512, 512,
                      dec_ff2_b + (size_t)i * 512, A1 + (size_t)s * Rd * 512, 512, Rd, 512, 2048, 0);
            }
            ln_kernel<<<rows / 4, 256, 0, stream>>>(Yc, A1,
                 dec_ln3_g + (size_t)i * 512, dec_ln3_b + (size_t)i * 512, Yc, rows);
        }
        ln_kernel<<<rows / 4, 256, 0, stream>>>(Yc, nullptr, dec_fn_g, dec_fn_b, Yc, rows);
    }

    // map to FEAT=64 (fp32 path, N=64)
    gemm(Y, 512, w_map, 64, b_map, F, 64, 16384, 64, 512, 0);

    // ================= spatial GATv2 (fp32 GEMMs, error-sensitive tail) ====
    float* G  = scr;
    float* Hb = scr + 4194304;
    float* Ib = scr + 8388608;
    gemm(F, 64, g1_wl, 256, g1_bl, G,  256, 16384, 256, 64, 0);
    gemm(F, 64, g1_wr, 256, g1_br, Hb, 256, 16384, 256, 64, 0);
    gatv2_kernel<false><<<16384, 256, 0, stream>>>(G, Hb, g1_att, g1_bias, off, eid, esrc, Ib, nullptr);
    gemm(Ib, 256, g2_wl, 256, g2_bl, G,  256, 16384, 256, 256, 0);
    gemm(Ib, 256, g2_wr, 256, g2_br, Hb, 256, 16384, 256, 256, 0);
    gatv2_kernel<true><<<16384, 256, 0, stream>>>(G, Hb, g2_att, g2_bias, off, eid, esrc,
                                                  nullptr, (float*)d_out);

    diag_kernel<<<1, 64, 0, stream>>>(X, Y, F, Ib, G, (float*)d_out);
}

// Round 6
// 11098.212 us; speedup vs baseline: 2.8008x; 1.8054x over previous
//
#include <hip/hip_runtime.h>
#include <hip/hip_bf16.h>

// Problem constants
#define NHEAD 8
#define SLEN 64
#define TLEN 32
#define NNODE 512
#define NEDGE 16384
#define NLAYER 4

typedef __attribute__((ext_vector_type(8))) __bf16 bf16x8;
typedef __attribute__((ext_vector_type(4))) __bf16 bf16x4;
typedef __attribute__((ext_vector_type(4))) float  f32x4;

// ---------------------------------------------------------------------------
// bf16 MFMA GEMM: C[M,N] = A[M,K] @ B[K,N] + bias[N], optional relu.
// A,B fp32 in HBM, converted to bf16 during LDS staging. Accum fp32 (MFMA).
// BM=BN=128, BK=64, 256 threads = 4 waves (2x2), wave tile 64x64 (4x4 frags
// of 16x16x32). Requires M%128==0, N%128==0, K%64==0.
// ---------------------------------------------------------------------------
__global__ __launch_bounds__(256) void gemm_mfma(
    const float* __restrict__ A, int lda,
    const float* __restrict__ B, int ldb,
    const float* __restrict__ bias,
    float* __restrict__ C, int ldc,
    int M, int N, int K, int relu)
{
    __shared__ __bf16 As[128][80];   // [row][k], stride 160B (16B-aligned)
    __shared__ __bf16 Bs[128][80];   // [col][k] (transposed during staging)
    const int tid  = threadIdx.x;
    const int wid  = tid >> 6;
    const int lane = tid & 63;
    const int wr = wid >> 1, wc = wid & 1;
    const int m0 = blockIdx.y * 128, n0 = blockIdx.x * 128;

    const int a_k4 = (tid & 15) * 4;
    const int a_r  = tid >> 4;
    const int b_nb = (tid & 15) * 8;
    const int b_kb = (tid >> 4) * 4;

    const int lr = lane & 15;
    const int kg = (lane >> 4) * 8;

    f32x4 acc[4][4];
    #pragma unroll
    for (int m = 0; m < 4; ++m)
        #pragma unroll
        for (int n = 0; n < 4; ++n)
            acc[m][n] = (f32x4){0.0f, 0.0f, 0.0f, 0.0f};

    for (int k0 = 0; k0 < K; k0 += 64) {
        #pragma unroll
        for (int i = 0; i < 8; ++i) {
            const int row = a_r + i * 16;
            const float4 v = *reinterpret_cast<const float4*>(
                &A[(size_t)(m0 + row) * lda + k0 + a_k4]);
            bf16x4 w;
            w[0] = (__bf16)v.x; w[1] = (__bf16)v.y;
            w[2] = (__bf16)v.z; w[3] = (__bf16)v.w;
            *reinterpret_cast<bf16x4*>(&As[row][a_k4]) = w;
        }
        __bf16 bv[4][8];
        #pragma unroll
        for (int dk = 0; dk < 4; ++dk) {
            const size_t roff = (size_t)(k0 + b_kb + dk) * ldb + n0 + b_nb;
            const float4 u0 = *reinterpret_cast<const float4*>(&B[roff]);
            const float4 u1 = *reinterpret_cast<const float4*>(&B[roff + 4]);
            bv[dk][0] = (__bf16)u0.x; bv[dk][1] = (__bf16)u0.y;
            bv[dk][2] = (__bf16)u0.z; bv[dk][3] = (__bf16)u0.w;
            bv[dk][4] = (__bf16)u1.x; bv[dk][5] = (__bf16)u1.y;
            bv[dk][6] = (__bf16)u1.z; bv[dk][7] = (__bf16)u1.w;
        }
        #pragma unroll
        for (int dn = 0; dn < 8; ++dn) {
            bf16x4 w;
            w[0] = bv[0][dn]; w[1] = bv[1][dn]; w[2] = bv[2][dn]; w[3] = bv[3][dn];
            *reinterpret_cast<bf16x4*>(&Bs[b_nb + dn][b_kb]) = w;
        }
        __syncthreads();
        #pragma unroll
        for (int kk = 0; kk < 64; kk += 32) {
            bf16x8 fa[4], fb[4];
            #pragma unroll
            for (int m = 0; m < 4; ++m)
                fa[m] = *reinterpret_cast<const bf16x8*>(&As[wr * 64 + m * 16 + lr][kk + kg]);
            #pragma unroll
            for (int n = 0; n < 4; ++n)
                fb[n] = *reinterpret_cast<const bf16x8*>(&Bs[wc * 64 + n * 16 + lr][kk + kg]);
            #pragma unroll
            for (int m = 0; m < 4; ++m)
                #pragma unroll
                for (int n = 0; n < 4; ++n)
                    acc[m][n] = __builtin_amdgcn_mfma_f32_16x16x32_bf16(
                        fa[m], fb[n], acc[m][n], 0, 0, 0);
        }
        __syncthreads();
    }

    const int cr = (lane >> 4) * 4;
    const int cc = lane & 15;
    #pragma unroll
    for (int n = 0; n < 4; ++n) {
        const int gcol = n0 + wc * 64 + n * 16 + cc;
        const float bb = bias[gcol];
        #pragma unroll
        for (int m = 0; m < 4; ++m) {
            #pragma unroll
            for (int j = 0; j < 4; ++j) {
                const int grow = m0 + wr * 64 + m * 16 + cr + j;
                float v = acc[m][n][j] + bb;
                if (relu) v = fmaxf(v, 0.0f);
                C[(size_t)grow * ldc + gcol] = v;
            }
        }
    }
}

// ---------------------------------------------------------------------------
// fp32 GEMM (small/odd shapes: src/tgt proj, w_map, GAT g1/g2)
// ---------------------------------------------------------------------------
__global__ __launch_bounds__(256) void gemm_bias(
    const float* __restrict__ A, int lda,
    const float* __restrict__ B, int ldb,
    const float* __restrict__ bias,
    float* __restrict__ C, int ldc,
    int M, int N, int K, int relu)
{
    __shared__ float As[16][68];
    __shared__ float Bs[16][68];
    const int tid = threadIdx.x;
    const int tx = tid & 15, ty = tid >> 4;
    const int m0 = blockIdx.y * 64, n0 = blockIdx.x * 64;
    const int liA_m = tid >> 2;
    const int liA_k = (tid & 3) * 4;
    const int liB_n = (tid & 15) * 4;
    const int liB_k = tid >> 4;
    float acc[4][4] = {};
    for (int k0 = 0; k0 < K; k0 += 16) {
        float4 av = *reinterpret_cast<const float4*>(&A[(size_t)(m0 + liA_m) * lda + k0 + liA_k]);
        float4 bv = *reinterpret_cast<const float4*>(&B[(size_t)(k0 + liB_k) * ldb + n0 + liB_n]);
        As[liA_k + 0][liA_m] = av.x;
        As[liA_k + 1][liA_m] = av.y;
        As[liA_k + 2][liA_m] = av.z;
        As[liA_k + 3][liA_m] = av.w;
        *reinterpret_cast<float4*>(&Bs[liB_k][liB_n]) = bv;
        __syncthreads();
        #pragma unroll
        for (int kk = 0; kk < 16; ++kk) {
            float4 a4 = *reinterpret_cast<const float4*>(&As[kk][ty * 4]);
            float4 b4 = *reinterpret_cast<const float4*>(&Bs[kk][tx * 4]);
            float a[4] = {a4.x, a4.y, a4.z, a4.w};
            float b[4] = {b4.x, b4.y, b4.z, b4.w};
            #pragma unroll
            for (int i = 0; i < 4; ++i)
                #pragma unroll
                for (int j = 0; j < 4; ++j)
                    acc[i][j] += a[i] * b[j];
        }
        __syncthreads();
    }
    #pragma unroll
    for (int i = 0; i < 4; ++i) {
        const int m = m0 + ty * 4 + i;
        #pragma unroll
        for (int j = 0; j < 4; ++j) {
            const int n = n0 + tx * 4 + j;
            float v = acc[i][j] + bias[n];
            if (relu) v = fmaxf(v, 0.0f);
            C[(size_t)m * ldc + n] = v;
        }
    }
}

// ---------------------------------------------------------------------------
__global__ __launch_bounds__(256) void permute_in(
    const float* __restrict__ in, float* __restrict__ out, int L, int CH, int total)
{
    const int idx = blockIdx.x * 256 + threadIdx.x;
    if (idx >= total) return;
    const int c = idx % CH;
    const int r = idx / CH;       // r = l*512 + n
    const int n = r & 511;
    const int l = r >> 9;
    out[((size_t)n * L + l) * CH + c] = in[idx];
}

// ---------------------------------------------------------------------------
// Fused MHA, node-major: block = (n_local, h). One wave, online softmax.
// In-place safe (O may alias Q region).
// ---------------------------------------------------------------------------
template<int LQ, int LK, bool CAUSAL>
__global__ __launch_bounds__(64) void attn_kernel(
    const float* __restrict__ Q, int ldq,
    const float* __restrict__ Kp, int ldk,
    const float* __restrict__ Vp, int ldv,
    float* __restrict__ O, int ldo)
{
    __shared__ float qs[LQ][68];
    __shared__ float ks[LK][68];
    __shared__ float vs[LK][68];
    const int n = blockIdx.x >> 3;
    const int h = blockIdx.x & 7;
    const int lane = threadIdx.x;
    const int col = h * 64 + lane;
    for (int r = 0; r < LQ; ++r) qs[r][lane] = Q[(size_t)(n * LQ + r) * ldq + col];
    for (int r = 0; r < LK; ++r) ks[r][lane] = Kp[(size_t)(n * LK + r) * ldk + col];
    for (int r = 0; r < LK; ++r) vs[r][lane] = Vp[(size_t)(n * LK + r) * ldv + col];
    __syncthreads();
    float o[64];
    if (lane < LQ) {
        float qr[64];
        #pragma unroll
        for (int j = 0; j < 64; ++j) { qr[j] = qs[lane][j]; o[j] = 0.0f; }
        float m = -1e30f, l = 0.0f;
        const int kend = CAUSAL ? (lane + 1) : LK;
        for (int kk = 0; kk < kend; ++kk) {
            float s = 0.0f;
            #pragma unroll
            for (int j = 0; j < 16; ++j) {
                float4 kv = *reinterpret_cast<const float4*>(&ks[kk][j * 4]);
                s += qr[4*j+0]*kv.x + qr[4*j+1]*kv.y + qr[4*j+2]*kv.z + qr[4*j+3]*kv.w;
            }
            s *= 0.125f;
            const float mn = fmaxf(m, s);
            const float sc = expf(m - mn);
            const float p  = expf(s - mn);
            l = l * sc + p;
            #pragma unroll
            for (int j = 0; j < 16; ++j) {
                float4 vv = *reinterpret_cast<const float4*>(&vs[kk][j * 4]);
                o[4*j+0] = o[4*j+0] * sc + p * vv.x;
                o[4*j+1] = o[4*j+1] * sc + p * vv.y;
                o[4*j+2] = o[4*j+2] * sc + p * vv.z;
                o[4*j+3] = o[4*j+3] * sc + p * vv.w;
            }
            m = mn;
        }
        const float inv = 1.0f / l;
        #pragma unroll
        for (int j = 0; j < 64; ++j) o[j] *= inv;
    }
    __syncthreads();
    if (lane < LQ) {
        #pragma unroll
        for (int j = 0; j < 64; ++j) qs[lane][j] = o[j];
    }
    __syncthreads();
    for (int r = 0; r < LQ; ++r) O[(size_t)(n * LQ + r) * ldo + col] = qs[r][lane];
}

// ---------------------------------------------------------------------------
__global__ __launch_bounds__(256) void ln_kernel(
    const float* __restrict__ X, const float* __restrict__ R,
    const float* __restrict__ g, const float* __restrict__ b,
    float* __restrict__ out, int ntok)
{
    const int wid = threadIdx.x >> 6, lane = threadIdx.x & 63;
    const int row = blockIdx.x * 4 + wid;
    if (row >= ntok) return;
    const size_t base = (size_t)row * 512;
    float v[8];
    float s = 0.0f;
    const bool hasR = (R != nullptr);
    #pragma unroll
    for (int j = 0; j < 8; ++j) {
        float t = X[base + j * 64 + lane];
        if (hasR) t += R[base + j * 64 + lane];
        v[j] = t; s += t;
    }
    #pragma unroll
    for (int d = 32; d >= 1; d >>= 1) s += __shfl_xor(s, d, 64);
    const float mean = s * (1.0f / 512.0f);
    float vs = 0.0f;
    #pragma unroll
    for (int j = 0; j < 8; ++j) { const float d = v[j] - mean; vs += d * d; }
    #pragma unroll
    for (int d = 32; d >= 1; d >>= 1) vs += __shfl_xor(vs, d, 64);
    const float rstd = rsqrtf(vs * (1.0f / 512.0f) + 1e-5f);
    #pragma unroll
    for (int j = 0; j < 8; ++j) {
        const int c = j * 64 + lane;
        out[base + c] = (v[j] - mean) * rstd * g[c] + b[c];
    }
}

// ---------------------------------------------------------------------------
__global__ __launch_bounds__(256) void add_posenc(float* __restrict__ x, int L, int total)
{
    const int idx = blockIdx.x * 256 + threadIdx.x;
    if (idx >= total) return;
    const int d = idx & 511;
    const int row = idx >> 9;
    const int l = row % L;
    const int i2 = d & ~1;
    const float freq = expf(-9.210340371976184f * (float)i2 / 512.0f);
    const float a = (float)l * freq;
    x[idx] += (d & 1) ? cosf(a) : sinf(a);
}

// ---------------------------------------------------------------------------
__global__ void zero_ints(int* __restrict__ p, int n)
{
    const int i = blockIdx.x * 256 + threadIdx.x;
    if (i < n) p[i] = 0;
}

__global__ void count_deg(const int* __restrict__ edst, int* __restrict__ deg)
{
    const int e = blockIdx.x * 256 + threadIdx.x;
    if (e < NEDGE) atomicAdd(&deg[edst[e]], 1);
}

__global__ void scan512(const int* __restrict__ deg, int* __restrict__ off)
{
    __shared__ int s[512];
    const int tid = threadIdx.x;
    s[tid] = deg[tid];
    __syncthreads();
    for (int d = 1; d < 512; d <<= 1) {
        const int t = (tid >= d) ? s[tid - d] : 0;
        __syncthreads();
        s[tid] += t;
        __syncthreads();
    }
    off[tid + 1] = s[tid];
    if (tid == 0) off[0] = 0;
}

__global__ void fill_eid(const int* __restrict__ edst, const int* __restrict__ off,
                         int* __restrict__ cur, int* __restrict__ eid)
{
    const int e = blockIdx.x * 256 + threadIdx.x;
    if (e < NEDGE) {
        const int d = edst[e];
        const int pos = off[d] + atomicAdd(&cur[d], 1);
        eid[pos] = e;
    }
}

// ---------------------------------------------------------------------------
template<bool FINAL>
__global__ __launch_bounds__(256) void gatv2_kernel(
    const float* __restrict__ xl, const float* __restrict__ xr,
    const float* __restrict__ att, const float* __restrict__ bias,
    const int* __restrict__ off, const int* __restrict__ eid,
    const int* __restrict__ esrc,
    float* __restrict__ outf, float* __restrict__ outd)
{
    const int blk = blockIdx.x;       // t*NNODE + i
    const int i = blk & (NNODE - 1);
    const int t = blk >> 9;
    const int tid = threadIdx.x;
    const float xrv = xr[((size_t)i * TLEN + t) * 256 + tid];
    const float av = att[tid];
    const int e0 = off[i], e1 = off[i + 1];
    float m = -1e30f, den = 0.0f, acc = 0.0f;
    for (int idx = e0; idx < e1; ++idx) {
        const int e = eid[idx];
        const int s = esrc[e];
        const float xlv = xl[((size_t)s * TLEN + t) * 256 + tid];
        float z = xlv + xrv;
        z = (z > 0.0f) ? z : 0.2f * z;
        float w = z * av;
        #pragma unroll
        for (int d = 16; d >= 1; d >>= 1) w += __shfl_xor(w, d, 32);
        const float mn = fmaxf(m, w);
        const float sc = expf(m - mn);
        const float p  = expf(w - mn);
        den = den * sc + p;
        acc = acc * sc + p * xlv;
        m = mn;
    }
    float o = (den > 0.0f) ? acc / den : 0.0f;
    o += bias[tid];
    if (FINAL) {
        o = fmaxf(o, 0.0f);
        outd[(size_t)blk * 256 + tid] = o;
    } else {
        outf[((size_t)i * TLEN + t) * 256 + tid] = o;
    }
}

// ---------------------------------------------------------------------------
extern "C" void kernel_launch(void* const* d_in, const int* in_sizes, int n_in,
                              void* d_out, int out_size, void* d_ws, size_t ws_size,
                              hipStream_t stream)
{
    const float* src       = (const float*)d_in[0];
    const float* tgt       = (const float*)d_in[1];
    const float* w_enc_in  = (const float*)d_in[2];
    const float* b_enc_in  = (const float*)d_in[3];
    const float* w_dec_in  = (const float*)d_in[4];
    const float* b_dec_in  = (const float*)d_in[5];
    const float* w_map     = (const float*)d_in[6];
    const float* b_map     = (const float*)d_in[7];
    const float* enc_qkv_w = (const float*)d_in[8];
    const float* enc_qkv_b = (const float*)d_in[9];
    const float* enc_out_w = (const float*)d_in[10];
    const float* enc_out_b = (const float*)d_in[11];
    const float* enc_ff1_w = (const float*)d_in[12];
    const float* enc_ff1_b = (const float*)d_in[13];
    const float* enc_ff2_w = (const float*)d_in[14];
    const float* enc_ff2_b = (const float*)d_in[15];
    const float* enc_ln1_g = (const float*)d_in[16];
    const float* enc_ln1_b = (const float*)d_in[17];
    const float* enc_ln2_g = (const float*)d_in[18];
    const float* enc_ln2_b = (const float*)d_in[19];
    const float* enc_fn_g  = (const float*)d_in[20];
    const float* enc_fn_b  = (const float*)d_in[21];
    const float* dec_sa_qkv_w = (const float*)d_in[22];
    const float* dec_sa_qkv_b = (const float*)d_in[23];
    const float* dec_sa_out_w = (const float*)d_in[24];
    const float* dec_sa_out_b = (const float*)d_in[25];
    const float* dec_ca_qkv_w = (const float*)d_in[26];
    const float* dec_ca_qkv_b = (const float*)d_in[27];
    const float* dec_ca_out_w = (const float*)d_in[28];
    const float* dec_ca_out_b = (const float*)d_in[29];
    const float* dec_ff1_w = (const float*)d_in[30];
    const float* dec_ff1_b = (const float*)d_in[31];
    const float* dec_ff2_w = (const float*)d_in[32];
    const float* dec_ff2_b = (const float*)d_in[33];
    const float* dec_ln1_g = (const float*)d_in[34];
    const float* dec_ln1_b = (const float*)d_in[35];
    const float* dec_ln2_g = (const float*)d_in[36];
    const float* dec_ln2_b = (const float*)d_in[37];
    const float* dec_ln3_g = (const float*)d_in[38];
    const float* dec_ln3_b = (const float*)d_in[39];
    const float* dec_fn_g  = (const float*)d_in[40];
    const float* dec_fn_b  = (const float*)d_in[41];
    const float* g1_wl   = (const float*)d_in[42];
    const float* g1_wr   = (const float*)d_in[43];
    const float* g1_bl   = (const float*)d_in[44];
    const float* g1_br   = (const float*)d_in[45];
    const float* g1_att  = (const float*)d_in[46];
    const float* g1_bias = (const float*)d_in[47];
    const float* g2_wl   = (const float*)d_in[48];
    const float* g2_wr   = (const float*)d_in[49];
    const float* g2_bl   = (const float*)d_in[50];
    const float* g2_br   = (const float*)d_in[51];
    const float* g2_att  = (const float*)d_in[52];
    const float* g2_bias = (const float*)d_in[53];
    const int*   edge_index = (const int*)d_in[54];
    const int* esrc = edge_index;
    const int* edst = edge_index + NEDGE;

    // ---- adaptive node-chunk NC from ws_size (deterministic) ----
    // scratch pool = S1 (NC*64*1536) + S2 (NC*64*512) = 131072*NC floats,
    // but at least 12,582,912 floats for the GAT stage.
    const size_t persistF = 16777216 + 8388608 + 1048576;   // X + Y + F
    auto needBytes = [&](int NC) {
        size_t scrF = (size_t)131072 * NC;
        if (scrF < 12582912) scrF = 12582912;
        return (persistF + scrF + 18432) * 4;
    };
    int NC = 64;
    if      (ws_size >= needBytes(512)) NC = 512;
    else if (ws_size >= needBytes(256)) NC = 256;
    else if (ws_size >= needBytes(128)) NC = 128;
    const int nchunk = NNODE / NC;
    size_t scrF = (size_t)131072 * NC;
    if (scrF < 12582912) scrF = 12582912;

    // ---- workspace layout (floats) ----
    float* wsf = (float*)d_ws;
    float* X = wsf;                       // 16,777,216: encoder state -> MEM
    float* Y = X + 16777216;              //  8,388,608: decoder state
    float* F = Y + 8388608;               //  1,048,576: mapped dec out
    float* S = F + 1048576;               // scratch pool
    float* S1 = S;                        // NC*64*1536 floats
    float* S2 = S + (size_t)98304 * NC;   // NC*64*512 floats
    int* ipool = (int*)(S + scrF);
    int* deg = ipool;
    int* off = deg + 512;
    int* cur = off + 516;
    int* eid = cur + 512;

    auto gemm = [&](const float* A, int lda, const float* B, int ldb, const float* bias,
                    float* Cc, int ldc, int M, int N, int K, int relu) {
        dim3 grid((unsigned)(N / 64), (unsigned)(M / 64));
        gemm_bias<<<grid, 256, 0, stream>>>(A, lda, B, ldb, bias, Cc, ldc, M, N, K, relu);
    };
    auto gemmB = [&](const float* A, int lda, const float* B, int ldb, const float* bias,
                     float* Cc, int ldc, int M, int N, int K, int relu) {
        dim3 grid((unsigned)(N / 128), (unsigned)(M / 128));
        gemm_mfma<<<grid, 256, 0, stream>>>(A, lda, B, ldb, bias, Cc, ldc, M, N, K, relu);
    };

    // ---- CSR build ----
    zero_ints<<<8, 256, 0, stream>>>(ipool, 512 + 516 + 512);
    count_deg<<<NEDGE / 256, 256, 0, stream>>>(edst, deg);
    scan512<<<1, 512, 0, stream>>>(deg, off);
    fill_eid<<<NEDGE / 256, 256, 0, stream>>>(edst, off, cur, eid);

    // ---- permute inputs to node-major, plain fp32 projections ----
    float* src_nm = S1;
    float* tgt_nm = S1 + 1048576;
    permute_in<<<4096, 256, 0, stream>>>(src, src_nm, SLEN, 32, 32768 * 32);
    permute_in<<<4096, 256, 0, stream>>>(tgt, tgt_nm, TLEN, 64, 16384 * 64);
    gemm(src_nm, 32, w_enc_in, 512, b_enc_in, X, 512, 32768, 512, 32, 0);
    gemm(tgt_nm, 64, w_dec_in, 512, b_dec_in, Y, 512, 16384, 512, 64, 0);
    add_posenc<<<(32768 * 512) / 256, 256, 0, stream>>>(X, SLEN, 32768 * 512);
    add_posenc<<<(16384 * 512) / 256, 256, 0, stream>>>(Y, TLEN, 16384 * 512);

    // ================= encoder =================
    for (int c = 0; c < nchunk; ++c) {
        float* Xc = X + (size_t)c * NC * 64 * 512;
        const int rows = NC * 64;
        for (int i = 0; i < NLAYER; ++i) {
            const float* qkvW = enc_qkv_w + (size_t)i * 512 * 1536;
            const float* qkvB = enc_qkv_b + (size_t)i * 1536;
            // fused QKV: rows x 1536
            gemmB(Xc, 512, qkvW, 1536, qkvB, S1, 1536, rows, 1536, 512, 0);
            attn_kernel<64, 64, false><<<NC * 8, 64, 0, stream>>>(
                S1, 1536, S1 + 512, 1536, S1 + 1024, 1536, S1, 1536);
            gemmB(S1, 1536, enc_out_w + (size_t)i * 512 * 512, 512, enc_out_b + (size_t)i * 512,
                  S2, 512, rows, 512, 512, 0);
            ln_kernel<<<rows / 4, 256, 0, stream>>>(Xc, S2,
                 enc_ln1_g + (size_t)i * 512, enc_ln1_b + (size_t)i * 512, Xc, rows);
            const int r2 = rows / 2;   // FFN half-chunks (mid fits in S1)
            for (int s = 0; s < 2; ++s) {
                gemmB(Xc + (size_t)s * r2 * 512, 512, enc_ff1_w + (size_t)i * 512 * 2048, 2048,
                      enc_ff1_b + (size_t)i * 2048, S1, 2048, r2, 2048, 512, 1);
                gemmB(S1, 2048, enc_ff2_w + (size_t)i * 2048 * 512, 512,
                      enc_ff2_b + (size_t)i * 512, S2 + (size_t)s * r2 * 512, 512, r2, 512, 2048, 0);
            }
            ln_kernel<<<rows / 4, 256, 0, stream>>>(Xc, S2,
                 enc_ln2_g + (size_t)i * 512, enc_ln2_b + (size_t)i * 512, Xc, rows);
        }
        ln_kernel<<<rows / 4, 256, 0, stream>>>(Xc, nullptr, enc_fn_g, enc_fn_b, Xc, rows);
    }
    // X is now MEM (node-major)

    // ================= decoder =================
    for (int c = 0; c < nchunk; ++c) {
        float* Yc = Y + (size_t)c * NC * 32 * 512;
        float* MEMc = X + (size_t)c * NC * 64 * 512;
        const int rowsD = NC * 32;
        const int rowsE = NC * 64;
        for (int i = 0; i < NLAYER; ++i) {
            // causal self-attention (fused QKV)
            gemmB(Yc, 512, dec_sa_qkv_w + (size_t)i * 512 * 1536, 1536,
                  dec_sa_qkv_b + (size_t)i * 1536, S1, 1536, rowsD, 1536, 512, 0);
            attn_kernel<32, 32, true><<<NC * 8, 64, 0, stream>>>(
                S1, 1536, S1 + 512, 1536, S1 + 1024, 1536, S1, 1536);
            gemmB(S1, 1536, dec_sa_out_w + (size_t)i * 512 * 512, 512, dec_sa_out_b + (size_t)i * 512,
                  S2, 512, rowsD, 512, 512, 0);
            ln_kernel<<<rowsD / 4, 256, 0, stream>>>(Yc, S2,
                 dec_ln1_g + (size_t)i * 512, dec_ln1_b + (size_t)i * 512, Yc, rowsD);
            // cross-attention: Q (rowsD x 512) + fused KV (rowsE x 1024)
            const float* caW = dec_ca_qkv_w + (size_t)i * 512 * 1536;
            const float* caB = dec_ca_qkv_b + (size_t)i * 1536;
            float* Qb  = S1;                          // rowsD*512 = 16384*NC
            float* KVb = S1 + (size_t)16384 * NC;     // rowsE*1024 = 65536*NC
            gemmB(Yc,   512, caW,       1536, caB,       Qb,  512,  rowsD, 512,  512, 0);
            gemmB(MEMc, 512, caW + 512, 1536, caB + 512, KVb, 1024, rowsE, 1024, 512, 0);
            attn_kernel<32, 64, false><<<NC * 8, 64, 0, stream>>>(
                Qb, 512, KVb, 1024, KVb + 512, 1024, Qb, 512);
            gemmB(Qb, 512, dec_ca_out_w + (size_t)i * 512 * 512, 512, dec_ca_out_b + (size_t)i * 512,
                  S2, 512, rowsD, 512, 512, 0);
            ln_kernel<<<rowsD / 4, 256, 0, stream>>>(Yc, S2,
                 dec_ln2_g + (size_t)i * 512, dec_ln2_b + (size_t)i * 512, Yc, rowsD);
            // FFN half-chunks
            const int r2 = rowsD / 2;
            for (int s = 0; s < 2; ++s) {
                gemmB(Yc + (size_t)s * r2 * 512, 512, dec_ff1_w + (size_t)i * 512 * 2048, 2048,
                      dec_ff1_b + (size_t)i * 2048, S1, 2048, r2, 2048, 512, 1);
                gemmB(S1, 2048, dec_ff2_w + (size_t)i * 2048 * 512, 512,
                      dec_ff2_b + (size_t)i * 512, S2 + (size_t)s * r2 * 512, 512, r2, 512, 2048, 0);
            }
            ln_kernel<<<rowsD / 4, 256, 0, stream>>>(Yc, S2,
                 dec_ln3_g + (size_t)i * 512, dec_ln3_b + (size_t)i * 512, Yc, rowsD);
        }
        ln_kernel<<<rowsD / 4, 256, 0, stream>>>(Yc, nullptr, dec_fn_g, dec_fn_b, Yc, rowsD);
    }

    // map to FEAT=64 (fp32 path, N=64)
    gemm(Y, 512, w_map, 64, b_map, F, 64, 16384, 64, 512, 0);

    // ================= spatial GATv2 (fp32 GEMMs) =================
    float* G  = S;
    float* Hb = S + 4194304;
    float* Ib = S + 8388608;
    gemm(F, 64, g1_wl, 256, g1_bl, G,  256, 16384, 256, 64, 0);
    gemm(F, 64, g1_wr, 256, g1_br, Hb, 256, 16384, 256, 64, 0);
    gatv2_kernel<false><<<16384, 256, 0, stream>>>(G, Hb, g1_att, g1_bias, off, eid, esrc, Ib, nullptr);
    gemm(Ib, 256, g2_wl, 256, g2_bl, G,  256, 16384, 256, 256, 0);
    gemm(Ib, 256, g2_wr, 256, g2_br, Hb, 256, 16384, 256, 256, 0);
    gatv2_kernel<true><<<16384, 256, 0, stream>>>(G, Hb, g2_att, g2_bias, off, eid, esrc,
                                                  nullptr, (float*)d_out);
}